// Round 4
// baseline (427.326 us; speedup 1.0000x reference)
//
#include <hip/hip_runtime.h>
#include <math.h>

#define NROWS 4096
#define DDIM  128
#define IMG_ELEMS 50331648LL   // 4096*3*64*64

typedef __attribute__((ext_vector_type(8))) short short8;   // 8 bf16 = 4 VGPRs
typedef __attribute__((ext_vector_type(4))) float floatx4;  // MFMA acc / float4 loads

// ws layout (bytes):
//   [0,64)        : 5 doubles  [0]=mse [1]=kld [2]=Spp [3]=Szz [4]=Spz
//   [64, +16K)    : nP (4096 f32 row norms of prior_z)
//   [.. , +16K)   : nZ
//   then 4 x 1MB  : Phi, Plo, Zhi, Zlo (bf16 as ushort, 4096x128,
//                   FRAGMENT-LINEAR layout: elem (r,c) at
//                   ((r>>4)*4 + (c>>5))*512 + (((c>>3)&3)*16 + (r&15))*8 + (c&7)
//                   so one MFMA fragment = contiguous 1KB in lane order)
#define WS_NP   64
#define WS_NZ   (WS_NP + 16384)
#define WS_PHI  (WS_NZ + 16384)
#define WS_PLO  (WS_PHI + 1048576)
#define WS_ZHI  (WS_PLO + 1048576)
#define WS_ZLO  (WS_ZHI + 1048576)

// Roles: even bids 0..2174 are streamers (1088 = 1024 mse + 64 kld),
// resident from t=0; all other bids are gram (2080 single tiles:
// 528 pp-upper + 528 zz-upper + 1024 pz-full).
#define GRAM_TILES   2080
#define MSE_ITEMS    1024
#define KLD_BLOCKS   64
#define STREAMERS    1088
#define TOTAL_BLOCKS (GRAM_TILES + STREAMERS)   // 3168

__device__ __forceinline__ unsigned short f2bf(float f) {
    unsigned u = __float_as_uint(f);
    unsigned r = (u + 0x7FFFu + ((u >> 16) & 1u)) >> 16;   // RNE
    return (unsigned short)r;
}
__device__ __forceinline__ float bf2f(unsigned short h) {
    return __uint_as_float(((unsigned)h) << 16);
}

__device__ __forceinline__ void block_reduce_atomic(double v, double* dst) {
    #pragma unroll
    for (int o = 32; o > 0; o >>= 1) v += __shfl_down(v, o);
    __shared__ double sm[4];
    int lane = threadIdx.x & 63, wv = threadIdx.x >> 6;
    if (lane == 0) sm[wv] = v;
    __syncthreads();
    if (threadIdx.x == 0) atomicAdd(dst, sm[0] + sm[1] + sm[2] + sm[3]);
}

// 2048 blocks x 256 threads; each wave owns one of 8192 rows (P then Z).
// Splits fp32 -> bf16 hi+lo into FRAGMENT-LINEAR layout, computes exact fp32
// row norms. Block 0 also zeroes the accumulator doubles.
__global__ __launch_bounds__(256) void prep_kernel(const float* __restrict__ P,
                                                   const float* __restrict__ Z,
                                                   char* __restrict__ wsb,
                                                   double* __restrict__ ws) {
    if (blockIdx.x == 0 && threadIdx.x < 8) ws[threadIdx.x] = 0.0;
    const int w = threadIdx.x >> 6;
    const int b = blockIdx.x * 4 + w;    // 0..8191
    const int row = b & 4095;
    const float* src;
    unsigned short *hi, *lo;
    float* nrm;
    if (b < 4096) {
        src = P + (size_t)row * DDIM;
        hi = (unsigned short*)(wsb + WS_PHI);
        lo = (unsigned short*)(wsb + WS_PLO);
        nrm = (float*)(wsb + WS_NP);
    } else {
        src = Z + (size_t)row * DDIM;
        hi = (unsigned short*)(wsb + WS_ZHI);
        lo = (unsigned short*)(wsb + WS_ZLO);
        nrm = (float*)(wsb + WS_NZ);
    }
    const int l = threadIdx.x & 63;      // lane holds cols 2l, 2l+1
    float2 v = ((const float2*)src)[l];
    unsigned short hx = f2bf(v.x), hy = f2bf(v.y);
    unsigned short lx = f2bf(v.x - bf2f(hx)), ly = f2bf(v.y - bf2f(hy));
    // fragment-linear destination (e and e+1 are contiguous: e in {0,2,4,6})
    const int rb = row >> 4, fr = row & 15;
    const int kb = l >> 4, fq = (l >> 2) & 3, e = (l & 3) * 2;
    const int dst = (rb * 4 + kb) * 512 + (fq * 16 + fr) * 8 + e;   // elems
    *(ushort2*)(hi + dst) = make_ushort2(hx, hy);
    *(ushort2*)(lo + dst) = make_ushort2(lx, ly);
    float s = v.x * v.x + v.y * v.y;
    #pragma unroll
    for (int o = 32; o > 0; o >>= 1) s += __shfl_down(s, o);
    if (l == 0) nrm[row] = s;
}

__global__ __launch_bounds__(256) void fused_kernel(char* __restrict__ wsb,
                                                    double* __restrict__ ws,
                                                    const floatx4* __restrict__ rc,
                                                    const floatx4* __restrict__ xx,
                                                    const floatx4* __restrict__ mu,
                                                    const floatx4* __restrict__ lv) {
    const int bid = blockIdx.x;
    const int tid = threadIdx.x, lane = tid & 63, w = tid >> 6;

    const bool is_stream = ((bid & 1) == 0) && ((bid >> 1) < STREAMERS);

    if (is_stream) {
        const int s = bid >> 1;              // 0..1087
        if (s < MSE_ITEMS) {
            // ------------- MSE role: contiguous 192KB chunk per array ------
            const long long base = (long long)s * 12288 + tid;
            floatx4 s0 = {0.f,0.f,0.f,0.f}, s1 = s0, s2 = s0, s3 = s0;
            #pragma unroll 1
            for (int it = 0; it < 12; ++it) {
                long long i = base + (long long)it * 1024;
                floatx4 a0 = __builtin_nontemporal_load(rc + i);
                floatx4 b0 = __builtin_nontemporal_load(xx + i);
                floatx4 a1 = __builtin_nontemporal_load(rc + i + 256);
                floatx4 b1 = __builtin_nontemporal_load(xx + i + 256);
                floatx4 a2 = __builtin_nontemporal_load(rc + i + 512);
                floatx4 b2 = __builtin_nontemporal_load(xx + i + 512);
                floatx4 a3 = __builtin_nontemporal_load(rc + i + 768);
                floatx4 b3 = __builtin_nontemporal_load(xx + i + 768);
                floatx4 d0 = a0 - b0, d1 = a1 - b1, d2 = a2 - b2, d3 = a3 - b3;
                s0 += d0 * d0; s1 += d1 * d1; s2 += d2 * d2; s3 += d3 * d3;
            }
            floatx4 st = (s0 + s1) + (s2 + s3);
            double v = ((double)st[0] + (double)st[1]) + ((double)st[2] + (double)st[3]);
            block_reduce_atomic(v, &ws[0]);
        } else {
            // ------------- KLD role: contiguous 32KB chunk per array -------
            const int k = s - MSE_ITEMS;     // 0..63
            const int i = k * 2048 + tid;
            float sm = 0.f;
            #pragma unroll
            for (int q = 0; q < 8; ++q) {
                floatx4 m = mu[i + q * 256], l = lv[i + q * 256];
                sm += (1.f + l[0] - m[0] * m[0] - __expf(l[0]) )
                    + (1.f + l[1] - m[1] * m[1] - __expf(l[1]) )
                    + (1.f + l[2] - m[2] * m[2] - __expf(l[2]) )
                    + (1.f + l[3] - m[3] * m[3] - __expf(l[3]) );
            }
            block_reduce_atomic((double)sm, &ws[1]);
        }
        return;
    }

    // ---------------- GRAM role: no LDS, no barriers -----------------------
    // tile id t in [0,2080): [0,528)=pp upper, [528,1056)=zz upper, rest pz
    const int t = (bid < 2176) ? (bid >> 1) : (bid - 1088);
    int g, by, bx;
    float wgt = 1.f;
    if (t < 1056) {
        g = (t < 528) ? 0 : 1;
        const int u = (t < 528) ? t : t - 528;
        int r = (int)((65.0f - sqrtf(4225.0f - 8.0f * (float)u)) * 0.5f);
        while ((r + 1) * (64 - r) / 2 <= u) ++r;    // cnt(r+1) <= u
        while (r * (65 - r) / 2 > u) --r;           // cnt(r) > u
        const int c = r + (u - r * (65 - r) / 2);
        by = r; bx = c;
        if (r != c) wgt = 2.f;                      // off-diagonal counts twice
    } else {
        g = 2;
        const int u = t - 1056;
        by = u >> 5; bx = u & 31;
    }

    const unsigned short* Phi = (const unsigned short*)(wsb + WS_PHI);
    const unsigned short* Plo = (const unsigned short*)(wsb + WS_PLO);
    const unsigned short* Zhi = (const unsigned short*)(wsb + WS_ZHI);
    const unsigned short* Zlo = (const unsigned short*)(wsb + WS_ZLO);
    const float* nP = (const float*)(wsb + WS_NP);
    const float* nZ = (const float*)(wsb + WS_NZ);
    const unsigned short *Ahi, *Alo, *Bhi, *Blo;
    const float *nI, *nJ;
    if (g == 0)      { Ahi = Phi; Alo = Plo; Bhi = Phi; Blo = Plo; nI = nP; nJ = nP; }
    else if (g == 1) { Ahi = Zhi; Alo = Zlo; Bhi = Zhi; Blo = Zlo; nI = nZ; nJ = nZ; }
    else             { Ahi = Phi; Alo = Plo; Bhi = Zhi; Blo = Zlo; nI = nP; nJ = nZ; }

    const int i0 = by * 128, j0 = bx * 128;
    const int qi = (w >> 1) * 64, qj = (w & 1) * 64;
    const int ra = (i0 + qi) >> 4;       // 16-row fragment block index, A side
    const int rbb = (j0 + qj) >> 4;      // B side

    floatx4 acc[4][4];
    const floatx4 zero4 = {0.f, 0.f, 0.f, 0.f};
    #pragma unroll
    for (int a = 0; a < 4; a++)
        #pragma unroll
        for (int b = 0; b < 4; b++) acc[a][b] = zero4;

    #pragma unroll
    for (int pass = 0; pass < 3; pass++) {
        const short8* As = (const short8*)((pass == 2) ? Alo : Ahi);  // hi,hi,lo
        const short8* Bs = (const short8*)((pass == 1) ? Blo : Bhi);  // hi,lo,hi
        #pragma unroll
        for (int kb = 0; kb < 4; kb++) {
            short8 af[4], bf[4];
            #pragma unroll
            for (int a = 0; a < 4; a++)
                af[a] = As[((ra + a) * 4 + kb) * 64 + lane];   // contiguous 1KB/wave
            #pragma unroll
            for (int b = 0; b < 4; b++)
                bf[b] = Bs[((rbb + b) * 4 + kb) * 64 + lane];
            #pragma unroll
            for (int a = 0; a < 4; a++)
                #pragma unroll
                for (int b = 0; b < 4; b++)
                    acc[a][b] = __builtin_amdgcn_mfma_f32_16x16x32_bf16(
                        af[a], bf[b], acc[a][b], 0, 0, 0);
        }
    }

    // epilogue: k_ij = exp(cc*(2*dot - ni - nj)), cc = 1/(D * 2*D*z_var)
    const float cc = 1.0f / 65536.0f;
    const int fr = lane & 15, fq = lane >> 4;
    float nj_[4];
    #pragma unroll
    for (int b = 0; b < 4; b++) nj_[b] = nJ[j0 + qj + b * 16 + fr];
    float sum = 0.f;
    #pragma unroll
    for (int a = 0; a < 4; a++) {
        #pragma unroll
        for (int r = 0; r < 4; r++) {
            const float ni = nI[i0 + qi + a * 16 + fq * 4 + r];
            #pragma unroll
            for (int b = 0; b < 4; b++)
                sum += expf(cc * (2.f * acc[a][b][r] - ni - nj_[b]));
        }
    }
    sum *= wgt;

    double v = (double)sum;
    #pragma unroll
    for (int o = 32; o > 0; o >>= 1) v += __shfl_down(v, o);
    __shared__ double red[4];
    if (lane == 0) red[w] = v;
    __syncthreads();
    if (tid == 0) atomicAdd(&ws[2 + g], red[0] + red[1] + red[2] + red[3]);
}

__global__ void finalize_kernel(const double* __restrict__ ws, float* __restrict__ out) {
    if (threadIdx.x == 0) {
        const double Nd = (double)NROWS;
        double recons_loss = ws[0] / (double)IMG_ELEMS;
        double kld = -0.5 * ws[1] / Nd;
        double mmd = (ws[2] + ws[3] - 2.0 * ws[4]) / (Nd * Nd);
        double bias_corr = Nd * (Nd - 1.0);
        double loss = 5.0 * recons_loss
                    + 1.5 * (1.0 / Nd) * kld
                    + (98.5 / bias_corr) * mmd;
        out[0] = (float)loss;
        out[1] = (float)recons_loss;
        out[2] = (float)mmd;
        out[3] = (float)(-kld);
    }
}

extern "C" void kernel_launch(void* const* d_in, const int* in_sizes, int n_in,
                              void* d_out, int out_size, void* d_ws, size_t ws_size,
                              hipStream_t stream) {
    const float* recons  = (const float*)d_in[0];
    const float* x       = (const float*)d_in[1];
    const float* z       = (const float*)d_in[2];
    const float* mu      = (const float*)d_in[3];
    const float* log_var = (const float*)d_in[4];
    const float* prior_z = (const float*)d_in[5];
    double* ws = (double*)d_ws;
    char* wsb = (char*)d_ws;
    float* out = (float*)d_out;

    prep_kernel<<<2048, 256, 0, stream>>>(prior_z, z, wsb, ws);
    fused_kernel<<<TOTAL_BLOCKS, 256, 0, stream>>>(wsb, ws,
                                                   (const floatx4*)recons,
                                                   (const floatx4*)x,
                                                   (const floatx4*)mu,
                                                   (const floatx4*)log_var);
    finalize_kernel<<<1, 64, 0, stream>>>(ws, out);
}